// Round 1
// baseline (386.911 us; speedup 1.0000x reference)
//
#include <hip/hip_runtime.h>
#include <math.h>

#define NN 384
#define CC 128
#define MT (NN * NN)   // 147456 pairs

typedef __attribute__((ext_vector_type(8))) short bf16x8;   // 8 bf16 = 4 VGPRs (MFMA A/B frag)
typedef __attribute__((ext_vector_type(4))) short short4v;  // 8B packed bf16 store
typedef __attribute__((ext_vector_type(4))) float f32x4;    // MFMA acc frag

__device__ __forceinline__ float bf2f(short u) {
  union { float f; unsigned i; } v; v.i = ((unsigned)(unsigned short)u) << 16; return v.f;
}
__device__ __forceinline__ short f2bf(float f) {
  union { float f; unsigned i; } v; v.f = f;
  unsigned x = v.i;
  return (short)((x + 0x7fffu + ((x >> 16) & 1u)) >> 16);  // RNE
}
__device__ __forceinline__ void cp16(void* lds, const void* g) {
  __builtin_amdgcn_global_load_lds(
      (const __attribute__((address_space(1))) void*)g,
      (__attribute__((address_space(3))) void*)lds, 16, 0, 0);
}
__device__ __forceinline__ float sigm(float x) { return 1.f / (1.f + __expf(-x)); }

// ---------------------------------------------------------------- K0: weights fp32 -> bf16
// layout: [proj_a, gate_a, proj_b, gate_b, gate_o, proj_o], each [128 out][128 in] row-major
__global__ __launch_bounds__(256) void k_wts(
    const float* __restrict__ w0, const float* __restrict__ w1,
    const float* __restrict__ w2, const float* __restrict__ w3,
    const float* __restrict__ w4, const float* __restrict__ w5,
    short* __restrict__ out)
{
  int idx = blockIdx.x * 256 + threadIdx.x;   // 0..98303
  const float* s;
  switch (idx >> 14) {
    case 0: s = w0; break; case 1: s = w1; break; case 2: s = w2; break;
    case 3: s = w3; break; case 4: s = w4; break; default: s = w5; break;
  }
  out[idx] = f2bf(s[idx & 16383]);
}

// ---------------------------------------------------------------- K1: LN(z) -> bf16 [p][c]
__global__ __launch_bounds__(256) void k_ln_in(
    const float* __restrict__ z, const float* __restrict__ lw,
    const float* __restrict__ lb, short* __restrict__ zn)
{
  const int wid = threadIdx.x >> 6, lane = threadIdx.x & 63;
  const size_t p = (size_t)blockIdx.x * 4 + wid;   // one wave per row
  const float2 v = ((const float2*)(z + p * CC))[lane];
  float s = v.x + v.y, sq = v.x * v.x + v.y * v.y;
  #pragma unroll
  for (int o = 32; o > 0; o >>= 1) { s += __shfl_xor(s, o); sq += __shfl_xor(sq, o); }
  const float mu = s * (1.f / 128.f);
  const float rstd = rsqrtf(sq * (1.f / 128.f) - mu * mu + 1e-5f);
  const float2 w2 = ((const float2*)lw)[lane];
  const float2 b2 = ((const float2*)lb)[lane];
  short2 o2;
  o2.x = f2bf((v.x - mu) * rstd * w2.x + b2.x);
  o2.y = f2bf((v.y - mu) * rstd * w2.y + b2.y);
  ((short2*)(zn + p * CC))[lane] = o2;
}

// ---------------------------------------------------------------- K2: fused linear(s)
// PAIRED: out[c][y0*384 + x0+m] = (proj+bp)*sigmoid(gate+bg)*mask[x,y]  (A rows = pairs (x0+r, y0))
// !PAIRED: out[c][p0+m]         = sigmoid(acc+bp)                      (A rows = pairs p0+r)
template<bool PAIRED>
__global__ __launch_bounds__(256) void k_lin(
    const short* __restrict__ zn, const short* __restrict__ Bw,
    const float* __restrict__ bias_p, const float* __restrict__ bias_g,
    const float* __restrict__ mask, short* __restrict__ outp)
{
  __shared__ short As[128 * 64];
  __shared__ short Bs[(PAIRED ? 256 : 128) * 64];
  __shared__ float mask_s[128];

  const int tid = threadIdx.x, wid = tid >> 6, lane = tid & 63;
  const int tile = blockIdx.x;
  const int y0 = tile / 3, x0 = (tile % 3) * 128, p0 = tile * 128;

  if (PAIRED && tid < 128) mask_s[tid] = mask[(size_t)(x0 + tid) * NN + y0];

  f32x4 accP[4][4], accG[4][4];
  #pragma unroll
  for (int i = 0; i < 4; ++i) {
    #pragma unroll
    for (int j = 0; j < 4; ++j) {
      accP[i][j] = f32x4{0.f, 0.f, 0.f, 0.f};
      accG[i][j] = f32x4{0.f, 0.f, 0.f, 0.f};
    }
  }
  const int wm = (wid >> 1) * 64, wn = (wid & 1) * 64;

  #pragma unroll
  for (int kk = 0; kk < 2; ++kk) {          // K=128 in two 64-slices
    __syncthreads();
    #pragma unroll
    for (int i = 0; i < 4; ++i) {           // A tile: 128 rows x 64 k (bf16)
      const int rbase = (i * 4 + wid) * 8;
      const int r = rbase + (lane >> 3);
      const size_t srow = PAIRED ? ((size_t)(x0 + r) * NN + y0) : (size_t)(p0 + r);
      cp16((char*)As + rbase * 128,
           (const char*)(zn + srow * CC) + kk * 128 + (lane & 7) * 16);
    }
    const int NR = PAIRED ? 8 : 4;          // B tile: (256|128) rows x 64 k
    #pragma unroll
    for (int i = 0; i < NR; ++i) {
      const int rbase = (i * 4 + wid) * 8;
      const int r = rbase + (lane >> 3);
      cp16((char*)Bs + rbase * 128,
           (const char*)(Bw + (size_t)r * CC) + kk * 128 + (lane & 7) * 16);
    }
    __syncthreads();
    #pragma unroll
    for (int ks = 0; ks < 2; ++ks) {
      const int krow = ks * 32 + (lane >> 4) * 8;
      bf16x8 a[4], bp[4], bg[4];
      #pragma unroll
      for (int f = 0; f < 4; ++f)
        a[f] = *(const bf16x8*)&As[(wm + f * 16 + (lane & 15)) * 64 + krow];
      #pragma unroll
      for (int f = 0; f < 4; ++f)
        bp[f] = *(const bf16x8*)&Bs[(wn + f * 16 + (lane & 15)) * 64 + krow];
      if (PAIRED) {
        #pragma unroll
        for (int f = 0; f < 4; ++f)
          bg[f] = *(const bf16x8*)&Bs[128 * 64 + (wn + f * 16 + (lane & 15)) * 64 + krow];
      }
      #pragma unroll
      for (int fm = 0; fm < 4; ++fm) {
        #pragma unroll
        for (int fn = 0; fn < 4; ++fn) {
          accP[fm][fn] = __builtin_amdgcn_mfma_f32_16x16x32_bf16(a[fm], bp[fn], accP[fm][fn], 0, 0, 0);
          if (PAIRED)
            accG[fm][fn] = __builtin_amdgcn_mfma_f32_16x16x32_bf16(a[fm], bg[fn], accG[fm][fn], 0, 0, 0);
        }
      }
    }
  }

  const size_t rowoff = PAIRED ? ((size_t)y0 * NN + x0) : (size_t)p0;
  #pragma unroll
  for (int fm = 0; fm < 4; ++fm) {
    #pragma unroll
    for (int fn = 0; fn < 4; ++fn) {
      const int c = wn + fn * 16 + (lane & 15);
      const int mb = wm + fm * 16 + (lane >> 4) * 4;
      const float bpv = bias_p[c];
      float bgv = 0.f;
      if (PAIRED) bgv = bias_g[c];
      short4v st;
      #pragma unroll
      for (int e = 0; e < 4; ++e) {
        float v;
        if (PAIRED) {
          const float pv = accP[fm][fn][e] + bpv;
          const float gv = accG[fm][fn][e] + bgv;
          v = pv * sigm(gv) * mask_s[mb + e];
        } else {
          v = sigm(accP[fm][fn][e] + bpv);
        }
        st[e] = f2bf(v);
      }
      *(short4v*)(outp + (size_t)c * MT + rowoff + mb) = st;
    }
  }
}

// ---------------------------------------------------------------- K3: per-channel triangle GEMM
// acc[m][n] = sum_k ws_a[c][j0+m][k] * ws_b[c][i0+n][k] = contracted[i0+n][j0+m][c]
__global__ __launch_bounds__(256) void k_tri(
    const short* __restrict__ wsa, const short* __restrict__ wsb,
    const float* __restrict__ mask, short* __restrict__ wsct)
{
  __shared__ short As[128 * 64], Bs[128 * 64];
  const int tid = threadIdx.x, wid = tid >> 6, lane = tid & 63;
  const int c = blockIdx.y;
  const int i0 = (blockIdx.x / 3) * 128, j0 = (blockIdx.x % 3) * 128;
  const short* Ab = wsa + (size_t)c * MT;   // rows j, stride 384
  const short* Bb = wsb + (size_t)c * MT;   // rows i, stride 384

  f32x4 acc[4][4];
  #pragma unroll
  for (int i = 0; i < 4; ++i) {
    #pragma unroll
    for (int j = 0; j < 4; ++j) acc[i][j] = f32x4{0.f, 0.f, 0.f, 0.f};
  }
  const int wm = (wid >> 1) * 64, wn = (wid & 1) * 64;

  for (int kt = 0; kt < 6; ++kt) {          // K=384 in 64-slices
    __syncthreads();
    #pragma unroll
    for (int i = 0; i < 4; ++i) {
      const int rbase = (i * 4 + wid) * 8;
      const int r = rbase + (lane >> 3);
      cp16((char*)As + rbase * 128,
           (const char*)(Ab + (size_t)(j0 + r) * NN) + kt * 128 + (lane & 7) * 16);
      cp16((char*)Bs + rbase * 128,
           (const char*)(Bb + (size_t)(i0 + r) * NN) + kt * 128 + (lane & 7) * 16);
    }
    __syncthreads();
    #pragma unroll
    for (int ks = 0; ks < 2; ++ks) {
      const int krow = ks * 32 + (lane >> 4) * 8;
      bf16x8 a[4], b[4];
      #pragma unroll
      for (int f = 0; f < 4; ++f) {
        a[f] = *(const bf16x8*)&As[(wm + f * 16 + (lane & 15)) * 64 + krow];
        b[f] = *(const bf16x8*)&Bs[(wn + f * 16 + (lane & 15)) * 64 + krow];
      }
      #pragma unroll
      for (int fm = 0; fm < 4; ++fm) {
        #pragma unroll
        for (int fn = 0; fn < 4; ++fn)
          acc[fm][fn] = __builtin_amdgcn_mfma_f32_16x16x32_bf16(a[fm], b[fn], acc[fm][fn], 0, 0, 0);
      }
    }
  }
  #pragma unroll
  for (int fm = 0; fm < 4; ++fm) {
    #pragma unroll
    for (int fn = 0; fn < 4; ++fn) {
      const int i = i0 + wn + fn * 16 + (lane & 15);     // n -> i
      const int jb = j0 + wm + fm * 16 + (lane >> 4) * 4; // m -> j (4 consecutive)
      const f32x4 mk = *(const f32x4*)(mask + (size_t)i * NN + jb);
      short4v st;
      #pragma unroll
      for (int e = 0; e < 4; ++e) st[e] = f2bf(acc[fm][fn][e] * mk[e]);
      *(short4v*)(wsct + (size_t)c * MT + (size_t)i * NN + jb) = st;
    }
  }
}

// ---------------------------------------------------------------- K3b: LN over c + transpose [c][p]->[p][c]
__global__ __launch_bounds__(256) void k_ln_out(
    const short* __restrict__ wsct, const float* __restrict__ lw,
    const float* __restrict__ lb, short* __restrict__ z2)
{
  __shared__ float T[128][65];   // +1 pad: column reads conflict-light
  const int tid = threadIdx.x;
  const int p0 = blockIdx.x * 64;

  #pragma unroll
  for (int rep = 0; rep < 4; ++rep) {       // stage 128c x 64p tile
    const int c = rep * 32 + (tid >> 3);
    const int pp = (tid & 7) * 8;
    const bf16x8 v = *(const bf16x8*)(wsct + (size_t)c * MT + p0 + pp);
    #pragma unroll
    for (int e = 0; e < 8; ++e) T[c][pp + e] = bf2f(v[e]);
  }
  __syncthreads();

  const int pl = tid >> 2, q = tid & 3;     // 4 threads per p-column
  float s = 0.f, sq = 0.f;
  #pragma unroll
  for (int ccd = 0; ccd < 32; ++ccd) {
    const float v = T[q * 32 + ccd][pl];
    s += v; sq += v * v;
  }
  s += __shfl_xor(s, 1); sq += __shfl_xor(sq, 1);
  s += __shfl_xor(s, 2); sq += __shfl_xor(sq, 2);
  const float mu = s * (1.f / 128.f);
  const float rstd = rsqrtf(sq * (1.f / 128.f) - mu * mu + 1e-5f);

  const size_t p = p0 + pl;
  #pragma unroll
  for (int v8 = 0; v8 < 4; ++v8) {          // each thread writes 32 c, vectorized
    const int cb = q * 32 + v8 * 8;
    bf16x8 st;
    #pragma unroll
    for (int e = 0; e < 8; ++e)
      st[e] = f2bf((T[cb + e][pl] - mu) * rstd * lw[cb + e] + lb[cb + e]);
    *(bf16x8*)(z2 + p * CC + cb) = st;
  }
}

// ---------------------------------------------------------------- K4: out = (z2 @ Wo^T + bo) * gate
__global__ __launch_bounds__(256) void k_out(
    const short* __restrict__ z2, const short* __restrict__ Bw,
    const float* __restrict__ bo, const short* __restrict__ gate,
    float* __restrict__ out)
{
  __shared__ short As[128 * 64], Bs[128 * 64];
  const int tid = threadIdx.x, wid = tid >> 6, lane = tid & 63;
  const int p0 = blockIdx.x * 128;

  f32x4 acc[4][4];
  #pragma unroll
  for (int i = 0; i < 4; ++i) {
    #pragma unroll
    for (int j = 0; j < 4; ++j) acc[i][j] = f32x4{0.f, 0.f, 0.f, 0.f};
  }
  const int wm = (wid >> 1) * 64, wn = (wid & 1) * 64;

  #pragma unroll
  for (int kk = 0; kk < 2; ++kk) {
    __syncthreads();
    #pragma unroll
    for (int i = 0; i < 4; ++i) {
      const int rbase = (i * 4 + wid) * 8;
      const int r = rbase + (lane >> 3);
      cp16((char*)As + rbase * 128,
           (const char*)(z2 + (size_t)(p0 + r) * CC) + kk * 128 + (lane & 7) * 16);
      cp16((char*)Bs + rbase * 128,
           (const char*)(Bw + (size_t)r * CC) + kk * 128 + (lane & 7) * 16);
    }
    __syncthreads();
    #pragma unroll
    for (int ks = 0; ks < 2; ++ks) {
      const int krow = ks * 32 + (lane >> 4) * 8;
      bf16x8 a[4], b[4];
      #pragma unroll
      for (int f = 0; f < 4; ++f) {
        a[f] = *(const bf16x8*)&As[(wm + f * 16 + (lane & 15)) * 64 + krow];
        b[f] = *(const bf16x8*)&Bs[(wn + f * 16 + (lane & 15)) * 64 + krow];
      }
      #pragma unroll
      for (int fm = 0; fm < 4; ++fm) {
        #pragma unroll
        for (int fn = 0; fn < 4; ++fn)
          acc[fm][fn] = __builtin_amdgcn_mfma_f32_16x16x32_bf16(a[fm], b[fn], acc[fm][fn], 0, 0, 0);
      }
    }
  }
  #pragma unroll
  for (int fm = 0; fm < 4; ++fm) {
    #pragma unroll
    for (int fn = 0; fn < 4; ++fn) {
      const int d = wn + fn * 16 + (lane & 15);
      const int mb = wm + fm * 16 + (lane >> 4) * 4;
      const float bd = bo[d];
      const short4v gv = *(const short4v*)(gate + (size_t)d * MT + p0 + mb);
      #pragma unroll
      for (int e = 0; e < 4; ++e)
        out[(size_t)(p0 + mb + e) * CC + d] = (acc[fm][fn][e] + bd) * bf2f(gv[e]);
    }
  }
}

// ----------------------------------------------------------------
extern "C" void kernel_launch(void* const* d_in, const int* in_sizes, int n_in,
                              void* d_out, int out_size, void* d_ws, size_t ws_size,
                              hipStream_t stream) {
  const float* z        = (const float*)d_in[0];
  const float* mask     = (const float*)d_in[1];
  const float* ln_in_w  = (const float*)d_in[2];
  const float* ln_in_b  = (const float*)d_in[3];
  const float* ln_out_w = (const float*)d_in[4];
  const float* ln_out_b = (const float*)d_in[5];
  const float* pa_w = (const float*)d_in[6];  const float* pa_b = (const float*)d_in[7];
  const float* ga_w = (const float*)d_in[8];  const float* ga_b = (const float*)d_in[9];
  const float* pb_w = (const float*)d_in[10]; const float* pb_b = (const float*)d_in[11];
  const float* gb_w = (const float*)d_in[12]; const float* gb_b = (const float*)d_in[13];
  const float* go_w = (const float*)d_in[14]; const float* go_b = (const float*)d_in[15];
  const float* po_w = (const float*)d_in[16]; const float* po_b = (const float*)d_in[17];

  char* ws = (char*)d_ws;
  const size_t SZ = (size_t)MT * CC * 2;     // 37.75 MB per bf16 plane
  short* zn   = (short*)(ws);                //  [p][c]   (aliased later by wsct)
  short* wsa  = (short*)(ws + SZ);           //  [c][y][x] (aliased later by z2)
  short* wsb  = (short*)(ws + 2 * SZ);       //  [c][y][x]
  short* wsg  = (short*)(ws + 3 * SZ);       //  [c][p]
  short* wts  = (short*)(ws + 4 * SZ);       //  6x[128][128] bf16
  short* wsct = zn;                          //  [c][i][j] — zn dead after k_lin
  short* z2   = wsa;                         //  [p][c]    — wsa dead after k_tri

  k_wts<<<384, 256, 0, stream>>>(pa_w, ga_w, pb_w, gb_w, go_w, po_w, wts);
  k_ln_in<<<MT / 4, 256, 0, stream>>>(z, ln_in_w, ln_in_b, zn);
  k_lin<true ><<<1152, 256, 0, stream>>>(zn, wts,             pa_b, ga_b, mask, wsa);
  k_lin<true ><<<1152, 256, 0, stream>>>(zn, wts + 2 * 16384, pb_b, gb_b, mask, wsb);
  k_lin<false><<<1152, 256, 0, stream>>>(zn, wts + 4 * 16384, go_b, nullptr, nullptr, wsg);
  k_tri<<<dim3(9, 128), 256, 0, stream>>>(wsa, wsb, mask, wsct);
  k_ln_out<<<MT / 64, 256, 0, stream>>>(wsct, ln_out_w, ln_out_b, z2);
  k_out<<<1152, 256, 0, stream>>>(z2, wts + 5 * 16384, po_b, wsg, (float*)d_out);
}

// Round 2
// 354.895 us; speedup vs baseline: 1.0902x; 1.0902x over previous
//
#include <hip/hip_runtime.h>
#include <math.h>

#define NN 384
#define CC 128
#define MT (NN * NN)   // 147456 pairs

typedef __attribute__((ext_vector_type(8))) short bf16x8;   // 8 bf16 = 4 VGPRs (MFMA A/B frag)
typedef __attribute__((ext_vector_type(4))) short short4v;  // 8B packed bf16 store
typedef __attribute__((ext_vector_type(4))) float f32x4;    // MFMA acc frag

__device__ __forceinline__ float bf2f(short u) {
  union { float f; unsigned i; } v; v.i = ((unsigned)(unsigned short)u) << 16; return v.f;
}
__device__ __forceinline__ short f2bf(float f) {
  union { float f; unsigned i; } v; v.f = f;
  unsigned x = v.i;
  return (short)((x + 0x7fffu + ((x >> 16) & 1u)) >> 16);  // RNE
}
__device__ __forceinline__ void cp16(void* lds, const void* g) {
  __builtin_amdgcn_global_load_lds(
      (const __attribute__((address_space(1))) void*)g,
      (__attribute__((address_space(3))) void*)lds, 16, 0, 0);
}
__device__ __forceinline__ float sigm(float x) { return 1.f / (1.f + __expf(-x)); }

// LDS tile geometry (all GEMM kernels): [rows][64 bf16] = 128B rows = 8 x 16B slots.
// Swizzle: LDS[row][slot] holds global slot (slot ^ (row&7)).
//  - staging (linear LDS dest): lane l covers row (l>>3), slot (l&7) -> fetch global
//    slot (l&7)^(l>>3).
//  - read of global slot u for row r: LDS slot u ^ (r&7). All fragment rows have
//    (row&7) == (lane&7), so 16 lanes spread over 8 16B slots -> 2-way (free).

// ---------------------------------------------------------------- K0: weights fp32 -> bf16
__global__ __launch_bounds__(256) void k_wts(
    const float* __restrict__ w0, const float* __restrict__ w1,
    const float* __restrict__ w2, const float* __restrict__ w3,
    const float* __restrict__ w4, const float* __restrict__ w5,
    short* __restrict__ out)
{
  int idx = blockIdx.x * 256 + threadIdx.x;   // 0..98303
  const float* s;
  switch (idx >> 14) {
    case 0: s = w0; break; case 1: s = w1; break; case 2: s = w2; break;
    case 3: s = w3; break; case 4: s = w4; break; default: s = w5; break;
  }
  out[idx] = f2bf(s[idx & 16383]);
}

// ---------------------------------------------------------------- K1: LN(z) -> bf16 [p][c]
__global__ __launch_bounds__(256) void k_ln_in(
    const float* __restrict__ z, const float* __restrict__ lw,
    const float* __restrict__ lb, short* __restrict__ zn)
{
  const int wid = threadIdx.x >> 6, lane = threadIdx.x & 63;
  const size_t p = (size_t)blockIdx.x * 4 + wid;   // one wave per row
  const float2 v = ((const float2*)(z + p * CC))[lane];
  float s = v.x + v.y, sq = v.x * v.x + v.y * v.y;
  #pragma unroll
  for (int o = 32; o > 0; o >>= 1) { s += __shfl_xor(s, o); sq += __shfl_xor(sq, o); }
  const float mu = s * (1.f / 128.f);
  const float rstd = rsqrtf(sq * (1.f / 128.f) - mu * mu + 1e-5f);
  const float2 w2 = ((const float2*)lw)[lane];
  const float2 b2 = ((const float2*)lb)[lane];
  short2 o2;
  o2.x = f2bf((v.x - mu) * rstd * w2.x + b2.x);
  o2.y = f2bf((v.y - mu) * rstd * w2.y + b2.y);
  ((short2*)(zn + p * CC))[lane] = o2;
}

// ---------------------------------------------------------------- K2: fused linear(s)
// PAIRED: wsa/wsb[c][y0*384+x0+m] = (proj+bp)*sigmoid(gate+bg)*mask[x,y]
// !PAIRED: wsg[p0+m][c]           = sigmoid(acc+bp)          (gate plane, [p][c])
template<bool PAIRED>
__global__ __launch_bounds__(256) void k_lin(
    const short* __restrict__ zn, const short* __restrict__ Bw,
    const float* __restrict__ bias_p, const float* __restrict__ bias_g,
    const float* __restrict__ mask, short* __restrict__ outp)
{
  // union: staging (As 16K + Bs 32K|16K) vs transpose tile T[128][136] shorts (34816B)
  __shared__ char smem[PAIRED ? 49152 : 34816];
  __shared__ float mask_s[128];
  short* As = (short*)smem;
  short* Bs = (short*)(smem + 16384);
  short* T  = (short*)smem;

  const int tid = threadIdx.x, wid = tid >> 6, lane = tid & 63;
  const int tile = blockIdx.x;
  const int y0 = tile / 3, x0 = (tile % 3) * 128, p0 = tile * 128;

  if (PAIRED && tid < 128) mask_s[tid] = mask[(size_t)(x0 + tid) * NN + y0];

  f32x4 accP[4][4], accG[4][4];
  #pragma unroll
  for (int i = 0; i < 4; ++i) {
    #pragma unroll
    for (int j = 0; j < 4; ++j) {
      accP[i][j] = f32x4{0.f, 0.f, 0.f, 0.f};
      accG[i][j] = f32x4{0.f, 0.f, 0.f, 0.f};
    }
  }
  const int wm = (wid >> 1) * 64, wn = (wid & 1) * 64;
  const int slot = (lane & 7) ^ (lane >> 3);   // swizzled global source slot

  #pragma unroll
  for (int kk = 0; kk < 2; ++kk) {          // K=128 in two 64-slices
    __syncthreads();
    #pragma unroll
    for (int i = 0; i < 4; ++i) {           // A tile: 128 rows x 64 k
      const int rbase = (i * 4 + wid) * 8;
      const int r = rbase + (lane >> 3);
      const size_t srow = PAIRED ? ((size_t)(x0 + r) * NN + y0) : (size_t)(p0 + r);
      cp16((char*)As + rbase * 128,
           (const char*)(zn + srow * CC) + kk * 128 + slot * 16);
    }
    const int NR = PAIRED ? 8 : 4;          // B tile: (256|128) rows x 64 k
    #pragma unroll
    for (int i = 0; i < NR; ++i) {
      const int rbase = (i * 4 + wid) * 8;
      const int r = rbase + (lane >> 3);
      cp16((char*)Bs + rbase * 128,
           (const char*)(Bw + (size_t)r * CC) + kk * 128 + slot * 16);
    }
    __syncthreads();
    #pragma unroll
    for (int ks = 0; ks < 2; ++ks) {
      const int u = ks * 4 + (lane >> 4);           // global 16B slot index
      const int sl = (u ^ (lane & 7)) * 8;          // swizzled LDS read (elements)
      bf16x8 a[4], bp[4], bg[4];
      #pragma unroll
      for (int f = 0; f < 4; ++f)
        a[f] = *(const bf16x8*)&As[(wm + f * 16 + (lane & 15)) * 64 + sl];
      #pragma unroll
      for (int f = 0; f < 4; ++f)
        bp[f] = *(const bf16x8*)&Bs[(wn + f * 16 + (lane & 15)) * 64 + sl];
      if (PAIRED) {
        #pragma unroll
        for (int f = 0; f < 4; ++f)
          bg[f] = *(const bf16x8*)&Bs[128 * 64 + (wn + f * 16 + (lane & 15)) * 64 + sl];
      }
      #pragma unroll
      for (int fm = 0; fm < 4; ++fm) {
        #pragma unroll
        for (int fn = 0; fn < 4; ++fn) {
          accP[fm][fn] = __builtin_amdgcn_mfma_f32_16x16x32_bf16(a[fm], bp[fn], accP[fm][fn], 0, 0, 0);
          if (PAIRED)
            accG[fm][fn] = __builtin_amdgcn_mfma_f32_16x16x32_bf16(a[fm], bg[fn], accG[fm][fn], 0, 0, 0);
        }
      }
    }
  }

  // epilogue: transpose through LDS, then 256B-contiguous global rows
  __syncthreads();
  #pragma unroll
  for (int fm = 0; fm < 4; ++fm) {
    #pragma unroll
    for (int fn = 0; fn < 4; ++fn) {
      const int c = wn + fn * 16 + (lane & 15);
      const int mb = wm + fm * 16 + (lane >> 4) * 4;
      const float bpv = bias_p[c];
      if (PAIRED) {
        const float bgv = bias_g[c];
        short4v st;
        #pragma unroll
        for (int e = 0; e < 4; ++e) {
          const float pv = accP[fm][fn][e] + bpv;
          const float gv = accG[fm][fn][e] + bgv;
          st[e] = f2bf(pv * sigm(gv) * mask_s[mb + e]);
        }
        *(short4v*)&T[c * 136 + mb] = st;          // T[c][x]
      } else {
        #pragma unroll
        for (int e = 0; e < 4; ++e)
          T[(mb + e) * 136 + c] = f2bf(sigm(accP[fm][fn][e] + bpv));  // T[p][c]
      }
    }
  }
  __syncthreads();
  const size_t rowoff = (size_t)y0 * NN + x0;
  #pragma unroll
  for (int rep = 0; rep < 8; ++rep) {
    const int row = rep * 16 + (tid >> 4), chunk = tid & 15;
    const bf16x8 v = *(const bf16x8*)&T[row * 136 + chunk * 8];
    if (PAIRED)
      *(bf16x8*)(outp + (size_t)row * MT + rowoff + chunk * 8) = v;     // [c][..x]
    else
      *(bf16x8*)(outp + (size_t)(p0 + row) * CC + chunk * 8) = v;       // [p][..c]
  }
}

// ---------------------------------------------------------------- K3: per-channel triangle GEMM
// acc[m][n] = sum_k wsa[c][j0+m][k] * wsb[c][i0+n][k] = contracted[i0+n][j0+m][c]
__global__ __launch_bounds__(256) void k_tri(
    const short* __restrict__ wsa, const short* __restrict__ wsb,
    const float* __restrict__ mask, short* __restrict__ wsct)
{
  __shared__ char smem[34816];                // staging(32K) | T[128][136]
  short* As = (short*)smem;
  short* Bs = (short*)(smem + 16384);
  short* T  = (short*)smem;

  const int tid = threadIdx.x, wid = tid >> 6, lane = tid & 63;
  // XCD-chunked bijective remap: dispatch d -> orig o, 144 blocks (16 channels) per XCD
  const int o = (blockIdx.x & 7) * 144 + (blockIdx.x >> 3);
  const int c = o / 9, t9 = o % 9;
  const int i0 = (t9 / 3) * 128, j0 = (t9 % 3) * 128;
  const short* Ab = wsa + (size_t)c * MT;   // rows j, 384 k
  const short* Bb = wsb + (size_t)c * MT;   // rows i, 384 k

  f32x4 acc[4][4];
  #pragma unroll
  for (int i = 0; i < 4; ++i) {
    #pragma unroll
    for (int j = 0; j < 4; ++j) acc[i][j] = f32x4{0.f, 0.f, 0.f, 0.f};
  }
  const int wm = (wid >> 1) * 64, wn = (wid & 1) * 64;
  const int slot = (lane & 7) ^ (lane >> 3);

  for (int kt = 0; kt < 6; ++kt) {          // K=384 in 64-slices
    __syncthreads();
    #pragma unroll
    for (int i = 0; i < 4; ++i) {
      const int rbase = (i * 4 + wid) * 8;
      const int r = rbase + (lane >> 3);
      cp16((char*)As + rbase * 128,
           (const char*)(Ab + (size_t)(j0 + r) * NN) + kt * 128 + slot * 16);
      cp16((char*)Bs + rbase * 128,
           (const char*)(Bb + (size_t)(i0 + r) * NN) + kt * 128 + slot * 16);
    }
    __syncthreads();
    #pragma unroll
    for (int ks = 0; ks < 2; ++ks) {
      const int u = ks * 4 + (lane >> 4);
      const int sl = (u ^ (lane & 7)) * 8;
      bf16x8 a[4], b[4];
      #pragma unroll
      for (int f = 0; f < 4; ++f) {
        a[f] = *(const bf16x8*)&As[(wm + f * 16 + (lane & 15)) * 64 + sl];
        b[f] = *(const bf16x8*)&Bs[(wn + f * 16 + (lane & 15)) * 64 + sl];
      }
      #pragma unroll
      for (int fm = 0; fm < 4; ++fm) {
        #pragma unroll
        for (int fn = 0; fn < 4; ++fn)
          acc[fm][fn] = __builtin_amdgcn_mfma_f32_16x16x32_bf16(a[fm], b[fn], acc[fm][fn], 0, 0, 0);
      }
    }
  }

  __syncthreads();
  #pragma unroll
  for (int fm = 0; fm < 4; ++fm) {
    #pragma unroll
    for (int fn = 0; fn < 4; ++fn) {
      const int il = wn + fn * 16 + (lane & 15);          // n -> i (local)
      const int jb = wm + fm * 16 + (lane >> 4) * 4;      // m -> j (4 consecutive)
      const f32x4 mk = *(const f32x4*)(mask + (size_t)(i0 + il) * NN + j0 + jb);
      short4v st;
      #pragma unroll
      for (int e = 0; e < 4; ++e) st[e] = f2bf(acc[fm][fn][e] * mk[e]);
      *(short4v*)&T[il * 136 + jb] = st;                  // T[i][j]
    }
  }
  __syncthreads();
  #pragma unroll
  for (int rep = 0; rep < 8; ++rep) {
    const int row = rep * 16 + (tid >> 4), chunk = tid & 15;
    const bf16x8 v = *(const bf16x8*)&T[row * 136 + chunk * 8];
    *(bf16x8*)(wsct + (size_t)c * MT + (size_t)(i0 + row) * NN + j0 + chunk * 8) = v;
  }
}

// ---------------------------------------------------------------- K3b: LN over c + transpose [c][p]->[p][c]
__global__ __launch_bounds__(256) void k_ln_out(
    const short* __restrict__ wsct, const float* __restrict__ lw,
    const float* __restrict__ lb, short* __restrict__ z2)
{
  __shared__ float T[128][65];
  const int tid = threadIdx.x;
  const int p0 = blockIdx.x * 64;

  #pragma unroll
  for (int rep = 0; rep < 4; ++rep) {       // stage 128c x 64p tile
    const int c = rep * 32 + (tid >> 3);
    const int pp = (tid & 7) * 8;
    const bf16x8 v = *(const bf16x8*)(wsct + (size_t)c * MT + p0 + pp);
    #pragma unroll
    for (int e = 0; e < 8; ++e) T[c][pp + e] = bf2f(v[e]);
  }
  __syncthreads();

  const int pl = tid >> 2, q = tid & 3;     // 4 threads per p-column
  float s = 0.f, sq = 0.f;
  #pragma unroll
  for (int ccd = 0; ccd < 32; ++ccd) {
    const float v = T[q * 32 + ccd][pl];
    s += v; sq += v * v;
  }
  s += __shfl_xor(s, 1); sq += __shfl_xor(sq, 1);
  s += __shfl_xor(s, 2); sq += __shfl_xor(sq, 2);
  const float mu = s * (1.f / 128.f);
  const float rstd = rsqrtf(sq * (1.f / 128.f) - mu * mu + 1e-5f);

  const size_t p = p0 + pl;
  #pragma unroll
  for (int v8 = 0; v8 < 4; ++v8) {
    const int cb = q * 32 + v8 * 8;
    bf16x8 st;
    #pragma unroll
    for (int e = 0; e < 8; ++e)
      st[e] = f2bf((T[cb + e][pl] - mu) * rstd * lw[cb + e] + lb[cb + e]);
    *(bf16x8*)(z2 + p * CC + cb) = st;
  }
}

// ---------------------------------------------------------------- K4: out = (z2 @ Wo^T + bo) * gate
__global__ __launch_bounds__(256) void k_out(
    const short* __restrict__ z2, const short* __restrict__ Bw,
    const float* __restrict__ bo, const short* __restrict__ gate,
    float* __restrict__ out)
{
  __shared__ short As[128 * 64], Bs[128 * 64];
  const int tid = threadIdx.x, wid = tid >> 6, lane = tid & 63;
  const int p0 = blockIdx.x * 128;

  f32x4 acc[4][4];
  #pragma unroll
  for (int i = 0; i < 4; ++i) {
    #pragma unroll
    for (int j = 0; j < 4; ++j) acc[i][j] = f32x4{0.f, 0.f, 0.f, 0.f};
  }
  const int wm = (wid >> 1) * 64, wn = (wid & 1) * 64;
  const int slot = (lane & 7) ^ (lane >> 3);

  #pragma unroll
  for (int kk = 0; kk < 2; ++kk) {
    __syncthreads();
    #pragma unroll
    for (int i = 0; i < 4; ++i) {
      const int rbase = (i * 4 + wid) * 8;
      const int r = rbase + (lane >> 3);
      cp16((char*)As + rbase * 128,
           (const char*)(z2 + (size_t)(p0 + r) * CC) + kk * 128 + slot * 16);
      cp16((char*)Bs + rbase * 128,
           (const char*)(Bw + (size_t)r * CC) + kk * 128 + slot * 16);
    }
    __syncthreads();
    #pragma unroll
    for (int ks = 0; ks < 2; ++ks) {
      const int u = ks * 4 + (lane >> 4);
      const int sl = (u ^ (lane & 7)) * 8;
      bf16x8 a[4], b[4];
      #pragma unroll
      for (int f = 0; f < 4; ++f) {
        a[f] = *(const bf16x8*)&As[(wm + f * 16 + (lane & 15)) * 64 + sl];
        b[f] = *(const bf16x8*)&Bs[(wn + f * 16 + (lane & 15)) * 64 + sl];
      }
      #pragma unroll
      for (int fm = 0; fm < 4; ++fm) {
        #pragma unroll
        for (int fn = 0; fn < 4; ++fn)
          acc[fm][fn] = __builtin_amdgcn_mfma_f32_16x16x32_bf16(a[fm], b[fn], acc[fm][fn], 0, 0, 0);
      }
    }
  }
  #pragma unroll
  for (int fm = 0; fm < 4; ++fm) {
    #pragma unroll
    for (int fn = 0; fn < 4; ++fn) {
      const int d = wn + fn * 16 + (lane & 15);
      const int mb = wm + fm * 16 + (lane >> 4) * 4;
      const float bd = bo[d];
      #pragma unroll
      for (int e = 0; e < 4; ++e) {
        const float g = bf2f(gate[(size_t)(p0 + mb + e) * CC + d]);   // [p][c], 32B/16 lanes
        out[(size_t)(p0 + mb + e) * CC + d] = (acc[fm][fn][e] + bd) * g;
      }
    }
  }
}

// ----------------------------------------------------------------
extern "C" void kernel_launch(void* const* d_in, const int* in_sizes, int n_in,
                              void* d_out, int out_size, void* d_ws, size_t ws_size,
                              hipStream_t stream) {
  const float* z        = (const float*)d_in[0];
  const float* mask     = (const float*)d_in[1];
  const float* ln_in_w  = (const float*)d_in[2];
  const float* ln_in_b  = (const float*)d_in[3];
  const float* ln_out_w = (const float*)d_in[4];
  const float* ln_out_b = (const float*)d_in[5];
  const float* pa_w = (const float*)d_in[6];  const float* pa_b = (const float*)d_in[7];
  const float* ga_w = (const float*)d_in[8];  const float* ga_b = (const float*)d_in[9];
  const float* pb_w = (const float*)d_in[10]; const float* pb_b = (const float*)d_in[11];
  const float* gb_w = (const float*)d_in[12]; const float* gb_b = (const float*)d_in[13];
  const float* go_w = (const float*)d_in[14]; const float* go_b = (const float*)d_in[15];
  const float* po_w = (const float*)d_in[16]; const float* po_b = (const float*)d_in[17];

  char* ws = (char*)d_ws;
  const size_t SZ = (size_t)MT * CC * 2;     // 37.75 MB per bf16 plane
  short* zn   = (short*)(ws);                //  [p][c]   (aliased later by wsct)
  short* wsa  = (short*)(ws + SZ);           //  [c][y][x] (aliased later by z2)
  short* wsb  = (short*)(ws + 2 * SZ);       //  [c][y][x]
  short* wsg  = (short*)(ws + 3 * SZ);       //  [p][c] gate plane
  short* wts  = (short*)(ws + 4 * SZ);       //  6x[128][128] bf16
  short* wsct = zn;                          //  [c][i][j] — zn dead after k_lin
  short* z2   = wsa;                         //  [p][c]    — wsa dead after k_tri

  k_wts<<<384, 256, 0, stream>>>(pa_w, ga_w, pb_w, gb_w, go_w, po_w, wts);
  k_ln_in<<<MT / 4, 256, 0, stream>>>(z, ln_in_w, ln_in_b, zn);
  k_lin<true ><<<1152, 256, 0, stream>>>(zn, wts,             pa_b, ga_b, mask, wsa);
  k_lin<true ><<<1152, 256, 0, stream>>>(zn, wts + 2 * 16384, pb_b, gb_b, mask, wsb);
  k_lin<false><<<1152, 256, 0, stream>>>(zn, wts + 4 * 16384, go_b, nullptr, nullptr, wsg);
  k_tri<<<1152, 256, 0, stream>>>(wsa, wsb, mask, wsct);
  k_ln_out<<<MT / 64, 256, 0, stream>>>(wsct, ln_out_w, ln_out_b, z2);
  k_out<<<1152, 256, 0, stream>>>(z2, wts + 5 * 16384, po_b, wsg, (float*)d_out);
}

// Round 3
// 329.223 us; speedup vs baseline: 1.1752x; 1.0780x over previous
//
#include <hip/hip_runtime.h>
#include <math.h>

#define NN 384
#define CC 128
#define MT (NN * NN)   // 147456 pairs

typedef __attribute__((ext_vector_type(8))) short bf16x8;   // 8 bf16 = 4 VGPRs (MFMA A/B frag)
typedef __attribute__((ext_vector_type(4))) short short4v;  // 8B packed bf16 store
typedef __attribute__((ext_vector_type(4))) float f32x4;    // MFMA acc frag

__device__ __forceinline__ float bf2f(short u) {
  union { float f; unsigned i; } v; v.i = ((unsigned)(unsigned short)u) << 16; return v.f;
}
__device__ __forceinline__ short f2bf(float f) {
  union { float f; unsigned i; } v; v.f = f;
  unsigned x = v.i;
  return (short)((x + 0x7fffu + ((x >> 16) & 1u)) >> 16);  // RNE
}
__device__ __forceinline__ void cp16(void* lds, const void* g) {
  __builtin_amdgcn_global_load_lds(
      (const __attribute__((address_space(1))) void*)g,
      (__attribute__((address_space(3))) void*)lds, 16, 0, 0);
}
__device__ __forceinline__ float sigm(float x) { return 1.f / (1.f + __expf(-x)); }

// LDS tile geometry (GEMM staging): [rows][64 bf16] = 128B rows = 8 x 16B slots.
// Swizzle: LDS[row][slot] holds global slot (slot ^ (row&7)).
//  - cp16 staging (linear LDS dest): lane l covers row (l>>3), slot (l&7) -> fetch
//    global slot (l&7)^(l>>3).
//  - read of global slot u for row r: LDS slot u ^ (r&7).

// ---------------------------------------------------------------- K0: weights fp32 -> bf16
__global__ __launch_bounds__(256) void k_wts(
    const float* __restrict__ w0, const float* __restrict__ w1,
    const float* __restrict__ w2, const float* __restrict__ w3,
    const float* __restrict__ w4, const float* __restrict__ w5,
    short* __restrict__ out)
{
  int idx = blockIdx.x * 256 + threadIdx.x;   // 0..98303
  const float* s;
  switch (idx >> 14) {
    case 0: s = w0; break; case 1: s = w1; break; case 2: s = w2; break;
    case 3: s = w3; break; case 4: s = w4; break; default: s = w5; break;
  }
  out[idx] = f2bf(s[idx & 16383]);
}

// ---------------------------------------------------------------- K1: LN(z) -> bf16 [p][c]
__global__ __launch_bounds__(256) void k_ln_in(
    const float* __restrict__ z, const float* __restrict__ lw,
    const float* __restrict__ lb, short* __restrict__ zn)
{
  const int wid = threadIdx.x >> 6, lane = threadIdx.x & 63;
  const size_t p = (size_t)blockIdx.x * 4 + wid;   // one wave per row
  const float2 v = ((const float2*)(z + p * CC))[lane];
  float s = v.x + v.y, sq = v.x * v.x + v.y * v.y;
  #pragma unroll
  for (int o = 32; o > 0; o >>= 1) { s += __shfl_xor(s, o); sq += __shfl_xor(sq, o); }
  const float mu = s * (1.f / 128.f);
  const float rstd = rsqrtf(sq * (1.f / 128.f) - mu * mu + 1e-5f);
  const float2 w2 = ((const float2*)lw)[lane];
  const float2 b2 = ((const float2*)lb)[lane];
  short2 o2;
  o2.x = f2bf((v.x - mu) * rstd * w2.x + b2.x);
  o2.y = f2bf((v.y - mu) * rstd * w2.y + b2.y);
  ((short2*)(zn + p * CC))[lane] = o2;
}

// ---------------------------------------------------------------- K2: paired linear
// wsa/wsb[c][y0*384+x0+m] = (proj+bp)*sigmoid(gate+bg)*mask[x,y]
__global__ __launch_bounds__(256) void k_lin(
    const short* __restrict__ zn, const short* __restrict__ Bw,
    const float* __restrict__ bias_p, const float* __restrict__ bias_g,
    const float* __restrict__ mask, short* __restrict__ outp)
{
  __shared__ char smem[49152];   // staging As 16K + Bs 32K | epilogue T[128][136]
  __shared__ float mask_s[128];
  short* As = (short*)smem;
  short* Bs = (short*)(smem + 16384);
  short* T  = (short*)smem;

  const int tid = threadIdx.x, wid = tid >> 6, lane = tid & 63;
  const int tile = blockIdx.x;
  const int y0 = tile / 3, x0 = (tile % 3) * 128;

  if (tid < 128) mask_s[tid] = mask[(size_t)(x0 + tid) * NN + y0];

  f32x4 accP[4][4], accG[4][4];
  #pragma unroll
  for (int i = 0; i < 4; ++i) {
    #pragma unroll
    for (int j = 0; j < 4; ++j) {
      accP[i][j] = f32x4{0.f, 0.f, 0.f, 0.f};
      accG[i][j] = f32x4{0.f, 0.f, 0.f, 0.f};
    }
  }
  const int wm = (wid >> 1) * 64, wn = (wid & 1) * 64;
  const int slot = (lane & 7) ^ (lane >> 3);   // swizzled global source slot

  #pragma unroll
  for (int kk = 0; kk < 2; ++kk) {          // K=128 in two 64-slices
    __syncthreads();
    #pragma unroll
    for (int i = 0; i < 4; ++i) {           // A tile: 128 rows x 64 k
      const int rbase = (i * 4 + wid) * 8;
      const int r = rbase + (lane >> 3);
      cp16((char*)As + rbase * 128,
           (const char*)(zn + ((size_t)(x0 + r) * NN + y0) * CC) + kk * 128 + slot * 16);
    }
    #pragma unroll
    for (int i = 0; i < 8; ++i) {           // B tile: 256 rows (proj|gate) x 64 k
      const int rbase = (i * 4 + wid) * 8;
      const int r = rbase + (lane >> 3);
      cp16((char*)Bs + rbase * 128,
           (const char*)(Bw + (size_t)r * CC) + kk * 128 + slot * 16);
    }
    __syncthreads();
    #pragma unroll
    for (int ks = 0; ks < 2; ++ks) {
      const int u = ks * 4 + (lane >> 4);           // global 16B slot index
      const int sl = (u ^ (lane & 7)) * 8;          // swizzled LDS read (elements)
      bf16x8 a[4], bp[4], bg[4];
      #pragma unroll
      for (int f = 0; f < 4; ++f) {
        a[f]  = *(const bf16x8*)&As[(wm + f * 16 + (lane & 15)) * 64 + sl];
        bp[f] = *(const bf16x8*)&Bs[(wn + f * 16 + (lane & 15)) * 64 + sl];
        bg[f] = *(const bf16x8*)&Bs[128 * 64 + (wn + f * 16 + (lane & 15)) * 64 + sl];
      }
      #pragma unroll
      for (int fm = 0; fm < 4; ++fm) {
        #pragma unroll
        for (int fn = 0; fn < 4; ++fn) {
          accP[fm][fn] = __builtin_amdgcn_mfma_f32_16x16x32_bf16(a[fm], bp[fn], accP[fm][fn], 0, 0, 0);
          accG[fm][fn] = __builtin_amdgcn_mfma_f32_16x16x32_bf16(a[fm], bg[fn], accG[fm][fn], 0, 0, 0);
        }
      }
    }
  }

  // epilogue: transpose through LDS, then 256B-contiguous global rows
  __syncthreads();
  #pragma unroll
  for (int fm = 0; fm < 4; ++fm) {
    #pragma unroll
    for (int fn = 0; fn < 4; ++fn) {
      const int c = wn + fn * 16 + (lane & 15);
      const int mb = wm + fm * 16 + (lane >> 4) * 4;
      const float bpv = bias_p[c];
      const float bgv = bias_g[c];
      short4v st;
      #pragma unroll
      for (int e = 0; e < 4; ++e) {
        const float pv = accP[fm][fn][e] + bpv;
        const float gv = accG[fm][fn][e] + bgv;
        st[e] = f2bf(pv * sigm(gv) * mask_s[mb + e]);
      }
      *(short4v*)&T[c * 136 + mb] = st;          // T[c][x]
    }
  }
  __syncthreads();
  const size_t rowoff = (size_t)y0 * NN + x0;
  #pragma unroll
  for (int rep = 0; rep < 8; ++rep) {
    const int row = rep * 16 + (tid >> 4), chunk = tid & 15;
    const bf16x8 v = *(const bf16x8*)&T[row * 136 + chunk * 8];
    *(bf16x8*)(outp + (size_t)row * MT + rowoff + chunk * 8) = v;     // [c][..x]
  }
}

// ---------------------------------------------------------------- K3: per-channel triangle GEMM
// acc[m][n] = sum_k wsa[c][j0+m][k] * wsb[c][i0+n][k] = contracted[i0+n][j0+m][c]
__global__ __launch_bounds__(256) void k_tri(
    const short* __restrict__ wsa, const short* __restrict__ wsb,
    const float* __restrict__ mask, short* __restrict__ wsct)
{
  __shared__ char smem[34816];                // staging(32K) | T[128][136]
  short* As = (short*)smem;
  short* Bs = (short*)(smem + 16384);
  short* T  = (short*)smem;

  const int tid = threadIdx.x, wid = tid >> 6, lane = tid & 63;
  // XCD-chunked bijective remap: 144 consecutive orig blocks (16 channels) per XCD
  const int o = (blockIdx.x & 7) * 144 + (blockIdx.x >> 3);
  const int c = o / 9, t9 = o % 9;
  const int i0 = (t9 / 3) * 128, j0 = (t9 % 3) * 128;
  const short* Ab = wsa + (size_t)c * MT;   // rows j, 384 k
  const short* Bb = wsb + (size_t)c * MT;   // rows i, 384 k

  f32x4 acc[4][4];
  #pragma unroll
  for (int i = 0; i < 4; ++i) {
    #pragma unroll
    for (int j = 0; j < 4; ++j) acc[i][j] = f32x4{0.f, 0.f, 0.f, 0.f};
  }
  const int wm = (wid >> 1) * 64, wn = (wid & 1) * 64;
  const int slot = (lane & 7) ^ (lane >> 3);

  for (int kt = 0; kt < 6; ++kt) {          // K=384 in 64-slices
    __syncthreads();
    #pragma unroll
    for (int i = 0; i < 4; ++i) {
      const int rbase = (i * 4 + wid) * 8;
      const int r = rbase + (lane >> 3);
      cp16((char*)As + rbase * 128,
           (const char*)(Ab + (size_t)(j0 + r) * NN) + kt * 128 + slot * 16);
      cp16((char*)Bs + rbase * 128,
           (const char*)(Bb + (size_t)(i0 + r) * NN) + kt * 128 + slot * 16);
    }
    __syncthreads();
    #pragma unroll
    for (int ks = 0; ks < 2; ++ks) {
      const int u = ks * 4 + (lane >> 4);
      const int sl = (u ^ (lane & 7)) * 8;
      bf16x8 a[4], b[4];
      #pragma unroll
      for (int f = 0; f < 4; ++f) {
        a[f] = *(const bf16x8*)&As[(wm + f * 16 + (lane & 15)) * 64 + sl];
        b[f] = *(const bf16x8*)&Bs[(wn + f * 16 + (lane & 15)) * 64 + sl];
      }
      #pragma unroll
      for (int fm = 0; fm < 4; ++fm) {
        #pragma unroll
        for (int fn = 0; fn < 4; ++fn)
          acc[fm][fn] = __builtin_amdgcn_mfma_f32_16x16x32_bf16(a[fm], b[fn], acc[fm][fn], 0, 0, 0);
      }
    }
  }

  __syncthreads();
  #pragma unroll
  for (int fm = 0; fm < 4; ++fm) {
    #pragma unroll
    for (int fn = 0; fn < 4; ++fn) {
      const int il = wn + fn * 16 + (lane & 15);          // n -> i (local)
      const int jb = wm + fm * 16 + (lane >> 4) * 4;      // m -> j (4 consecutive)
      const f32x4 mk = *(const f32x4*)(mask + (size_t)(i0 + il) * NN + j0 + jb);
      short4v st;
      #pragma unroll
      for (int e = 0; e < 4; ++e) st[e] = f2bf(acc[fm][fn][e] * mk[e]);
      *(short4v*)&T[il * 136 + jb] = st;                  // T[i][j]
    }
  }
  __syncthreads();
  #pragma unroll
  for (int rep = 0; rep < 8; ++rep) {
    const int row = rep * 16 + (tid >> 4), chunk = tid & 15;
    const bf16x8 v = *(const bf16x8*)&T[row * 136 + chunk * 8];
    *(bf16x8*)(wsct + (size_t)c * MT + (size_t)(i0 + row) * NN + j0 + chunk * 8) = v;
  }
}

// ---------------------------------------------------------------- K4: fused LN-out + proj_o + gate_o
// out[p][d] = (proj_o(LN_c(wsct[:,p])) + bo) * sigmoid(gate_o(zn[p]) + bg)
__global__ __launch_bounds__(256) void k_fin(
    const short* __restrict__ wsct, const short* __restrict__ zn,
    const short* __restrict__ wpo, const short* __restrict__ wgo,
    const float* __restrict__ lw, const float* __restrict__ lb,
    const float* __restrict__ po_b, const float* __restrict__ go_b,
    float* __restrict__ out)
{
  // region0 (48KB): phases A-C: Tt[128][136] bf16 (34.8K) + lnw/lnb (1K)
  //                 phase D:    As2[128][64] (16K) + Bs[256][64] (32K)
  // region1 (32KB): A1 = LN'd contracted, swizzled [2(kk)][128][64]
  __shared__ char smem[81920];
  short* Tt    = (short*)smem;                   // [128][136]
  float* lnw_s = (float*)(smem + 34816);
  float* lnb_s = (float*)(smem + 35328);
  short* As2   = (short*)smem;                   // phase D
  short* Bs    = (short*)(smem + 16384);
  short* A1    = (short*)(smem + 49152);

  const int tid = threadIdx.x, wid = tid >> 6, lane = tid & 63;
  const size_t p0 = (size_t)blockIdx.x * 128;

  // ---- phase A: stage wsct[c][p0..p0+127] -> Tt[c][j], load LN weights
  #pragma unroll
  for (int rep = 0; rep < 8; ++rep) {
    const int c = rep * 16 + (tid >> 4), chunk = tid & 15;
    const bf16x8 v = *(const bf16x8*)(wsct + (size_t)c * MT + p0 + chunk * 8);
    *(bf16x8*)&Tt[c * 136 + chunk * 8] = v;
  }
  if (tid < 128) { lnw_s[tid] = lw[tid]; lnb_s[tid] = lb[tid]; }
  __syncthreads();

  // ---- phase B: LN stats per column (2 threads per column)
  const int pl = tid >> 1, q = tid & 1;
  float s = 0.f, sq = 0.f;
  #pragma unroll
  for (int cc = 0; cc < 64; ++cc) {
    const float v = bf2f(Tt[(q * 64 + cc) * 136 + pl]);
    s += v; sq += v * v;
  }
  s += __shfl_xor(s, 1); sq += __shfl_xor(sq, 1);
  const float mu = s * (1.f / 128.f);
  const float rstd = rsqrtf(sq * (1.f / 128.f) - mu * mu + 1e-5f);

  // ---- phase C: write normalized A1 (swizzled, kk-split by c)
  #pragma unroll
  for (int cb = 0; cb < 8; ++cb) {
    const int c0 = q * 64 + cb * 8;
    bf16x8 st;
    #pragma unroll
    for (int e = 0; e < 8; ++e) {
      const int c = c0 + e;
      st[e] = f2bf((bf2f(Tt[c * 136 + pl]) - mu) * rstd * lnw_s[c] + lnb_s[c]);
    }
    const int slotg = q * 8 + cb;            // global 16B-slot index 0..15
    const int kk = slotg >> 3, s3 = slotg & 7;
    *(bf16x8*)&A1[kk * 8192 + pl * 64 + (s3 ^ (pl & 7)) * 8] = st;
  }

  // ---- phase D: two GEMMs (proj_o on A1, gate_o on zn)
  f32x4 accO[4][4], accG[4][4];
  #pragma unroll
  for (int i = 0; i < 4; ++i) {
    #pragma unroll
    for (int j = 0; j < 4; ++j) {
      accO[i][j] = f32x4{0.f, 0.f, 0.f, 0.f};
      accG[i][j] = f32x4{0.f, 0.f, 0.f, 0.f};
    }
  }
  const int wm = (wid >> 1) * 64, wn = (wid & 1) * 64;
  const int slot = (lane & 7) ^ (lane >> 3);

  #pragma unroll
  for (int kk = 0; kk < 2; ++kk) {
    __syncthreads();   // kk=0: Tt dead (A-C done); kk=1: previous slice consumed
    #pragma unroll
    for (int i = 0; i < 4; ++i) {            // As2: zn tile 128 x 64
      const int rbase = (i * 4 + wid) * 8;
      const int r = rbase + (lane >> 3);
      cp16((char*)As2 + rbase * 128,
           (const char*)(zn + (p0 + r) * CC) + kk * 128 + slot * 16);
    }
    #pragma unroll
    for (int i = 0; i < 8; ++i) {            // Bs: proj_o rows 0-127, gate_o rows 128-255
      const int rbase = (i * 4 + wid) * 8;
      const int r = rbase + (lane >> 3);
      const short* wrow = (r < 128) ? (wpo + (size_t)r * CC) : (wgo + (size_t)(r - 128) * CC);
      cp16((char*)Bs + rbase * 128, (const char*)wrow + kk * 128 + slot * 16);
    }
    __syncthreads();
    #pragma unroll
    for (int ks = 0; ks < 2; ++ks) {
      const int u = ks * 4 + (lane >> 4);
      const int sl = (u ^ (lane & 7)) * 8;
      bf16x8 a1[4], a2[4], bo[4], bg[4];
      #pragma unroll
      for (int f = 0; f < 4; ++f) {
        const int row = wm + f * 16 + (lane & 15);
        a1[f] = *(const bf16x8*)&A1[kk * 8192 + row * 64 + sl];
        a2[f] = *(const bf16x8*)&As2[row * 64 + sl];
      }
      #pragma unroll
      for (int f = 0; f < 4; ++f) {
        const int row = wn + f * 16 + (lane & 15);
        bo[f] = *(const bf16x8*)&Bs[row * 64 + sl];
        bg[f] = *(const bf16x8*)&Bs[(128 + row) * 64 + sl];
      }
      #pragma unroll
      for (int fm = 0; fm < 4; ++fm) {
        #pragma unroll
        for (int fn = 0; fn < 4; ++fn) {
          accO[fm][fn] = __builtin_amdgcn_mfma_f32_16x16x32_bf16(a1[fm], bo[fn], accO[fm][fn], 0, 0, 0);
          accG[fm][fn] = __builtin_amdgcn_mfma_f32_16x16x32_bf16(a2[fm], bg[fn], accG[fm][fn], 0, 0, 0);
        }
      }
    }
  }

  // ---- epilogue: out[p][d] fp32, gated
  #pragma unroll
  for (int fm = 0; fm < 4; ++fm) {
    #pragma unroll
    for (int fn = 0; fn < 4; ++fn) {
      const int d = wn + fn * 16 + (lane & 15);
      const int mb = wm + fm * 16 + (lane >> 4) * 4;
      const float bd = po_b[d];
      const float gd = go_b[d];
      #pragma unroll
      for (int e = 0; e < 4; ++e) {
        const float g = sigm(accG[fm][fn][e] + gd);
        out[(p0 + mb + e) * CC + d] = (accO[fm][fn][e] + bd) * g;
      }
    }
  }
}

// ----------------------------------------------------------------
extern "C" void kernel_launch(void* const* d_in, const int* in_sizes, int n_in,
                              void* d_out, int out_size, void* d_ws, size_t ws_size,
                              hipStream_t stream) {
  const float* z        = (const float*)d_in[0];
  const float* mask     = (const float*)d_in[1];
  const float* ln_in_w  = (const float*)d_in[2];
  const float* ln_in_b  = (const float*)d_in[3];
  const float* ln_out_w = (const float*)d_in[4];
  const float* ln_out_b = (const float*)d_in[5];
  const float* pa_w = (const float*)d_in[6];  const float* pa_b = (const float*)d_in[7];
  const float* ga_w = (const float*)d_in[8];  const float* ga_b = (const float*)d_in[9];
  const float* pb_w = (const float*)d_in[10]; const float* pb_b = (const float*)d_in[11];
  const float* gb_w = (const float*)d_in[12]; const float* gb_b = (const float*)d_in[13];
  const float* go_w = (const float*)d_in[14]; const float* go_b = (const float*)d_in[15];
  const float* po_w = (const float*)d_in[16]; const float* po_b = (const float*)d_in[17];

  char* ws = (char*)d_ws;
  const size_t SZ = (size_t)MT * CC * 2;     // 37.75 MB per bf16 plane (ws = 302 MB, no aliasing)
  short* zn   = (short*)(ws);                //  [p][c]
  short* wsa  = (short*)(ws + SZ);           //  [c][y][x]
  short* wsb  = (short*)(ws + 2 * SZ);       //  [c][y][x]
  short* wsct = (short*)(ws + 3 * SZ);       //  [c][i][j]
  short* wts  = (short*)(ws + 4 * SZ);       //  6x[128][128] bf16

  k_wts<<<384, 256, 0, stream>>>(pa_w, ga_w, pb_w, gb_w, go_w, po_w, wts);
  k_ln_in<<<MT / 4, 256, 0, stream>>>(z, ln_in_w, ln_in_b, zn);
  k_lin<<<1152, 256, 0, stream>>>(zn, wts,             pa_b, ga_b, mask, wsa);
  k_lin<<<1152, 256, 0, stream>>>(zn, wts + 2 * 16384, pb_b, gb_b, mask, wsb);
  k_tri<<<1152, 256, 0, stream>>>(wsa, wsb, mask, wsct);
  k_fin<<<1152, 256, 0, stream>>>(wsct, zn, wts + 5 * 16384, wts + 4 * 16384,
                                  ln_out_w, ln_out_b, po_b, go_b, (float*)d_out);
}